// Round 8
// baseline (839.409 us; speedup 1.0000x reference)
//
#include <hip/hip_runtime.h>
#include <hip/hip_fp16.h>

#define RES 32
#define R3 32768
#define BATCH 16
#define CCH 64
#define NPTS 65536
#define NPTS4 16384
#define WIN 128

// ---------------- Stats phase A: partial coord sums ----------------
__global__ void statsA_kernel(const float* __restrict__ coords,
                              float* __restrict__ sums) {
    const int bid = blockIdx.x;      // 0..255
    const int b = bid >> 4;
    const int chunk = bid & 15;
    const int tid = threadIdx.x;     // 0..255
    const float* cb = coords + (size_t)b * 3 * NPTS;
    const int base4 = chunk * 1024;

    float sx = 0.f, sy = 0.f, sz = 0.f;
    for (int k = tid; k < 1024; k += 256) {
        float4 x4 = reinterpret_cast<const float4*>(cb)[base4 + k];
        float4 y4 = reinterpret_cast<const float4*>(cb + NPTS)[base4 + k];
        float4 z4 = reinterpret_cast<const float4*>(cb + 2 * NPTS)[base4 + k];
        sx += (x4.x + x4.y) + (x4.z + x4.w);
        sy += (y4.x + y4.y) + (y4.z + y4.w);
        sz += (z4.x + z4.y) + (z4.z + z4.w);
    }
    __shared__ float red[3][256];
    red[0][tid] = sx; red[1][tid] = sy; red[2][tid] = sz;
    __syncthreads();
    for (int s = 128; s > 0; s >>= 1) {
        if (tid < s) {
            red[0][tid] += red[0][tid + s];
            red[1][tid] += red[1][tid + s];
            red[2][tid] += red[2][tid + s];
        }
        __syncthreads();
    }
    if (tid == 0) {
        atomicAdd(&sums[b * 3 + 0], red[0][0]);
        atomicAdd(&sums[b * 3 + 1], red[1][0]);
        atomicAdd(&sums[b * 3 + 2], red[2][0]);
    }
}

// ---------------- Stats phase B: max squared radius ----------------
__global__ void statsB_kernel(const float* __restrict__ coords,
                              const float* __restrict__ sums,
                              unsigned int* __restrict__ r2bits) {
    const int bid = blockIdx.x;
    const int b = bid >> 4;
    const int chunk = bid & 15;
    const int tid = threadIdx.x;
    const float mx = sums[b * 3 + 0] * (1.0f / NPTS);
    const float my = sums[b * 3 + 1] * (1.0f / NPTS);
    const float mz = sums[b * 3 + 2] * (1.0f / NPTS);
    const float* cb = coords + (size_t)b * 3 * NPTS;
    const int base4 = chunk * 1024;

    float m = 0.f;
    for (int k = tid; k < 1024; k += 256) {
        float4 x4 = reinterpret_cast<const float4*>(cb)[base4 + k];
        float4 y4 = reinterpret_cast<const float4*>(cb + NPTS)[base4 + k];
        float4 z4 = reinterpret_cast<const float4*>(cb + 2 * NPTS)[base4 + k];
        float dx, dy, dz, r2;
        dx = x4.x - mx; dy = y4.x - my; dz = z4.x - mz; r2 = dx*dx + dy*dy + dz*dz; m = fmaxf(m, r2);
        dx = x4.y - mx; dy = y4.y - my; dz = z4.y - mz; r2 = dx*dx + dy*dy + dz*dz; m = fmaxf(m, r2);
        dx = x4.z - mx; dy = y4.z - my; dz = z4.z - mz; r2 = dx*dx + dy*dy + dz*dz; m = fmaxf(m, r2);
        dx = x4.w - mx; dy = y4.w - my; dz = z4.w - mz; r2 = dx*dx + dy*dy + dz*dz; m = fmaxf(m, r2);
    }
    __shared__ float red[256];
    red[tid] = m;
    __syncthreads();
    for (int s = 128; s > 0; s >>= 1) {
        if (tid < s) red[tid] = fmaxf(red[tid], red[tid + s]);
        __syncthreads();
    }
    if (tid == 0)
        atomicMax(&r2bits[b], __float_as_uint(red[0]));
}

// shared voxelization math (identical in norm_cnt / fallback)
__device__ __forceinline__ void vox_of(float xs, float ys, float zs,
                                       float mx, float my, float mz, float denom,
                                       float& xo, float& yo, float& zo, int& fo) {
    float x = ((xs - mx) / denom + 0.5f) * (float)RES;
    float y = ((ys - my) / denom + 0.5f) * (float)RES;
    float z = ((zs - mz) / denom + 0.5f) * (float)RES;
    x = fminf(fmaxf(x, 0.f), (float)(RES - 1));
    y = fminf(fmaxf(y, 0.f), (float)(RES - 1));
    z = fminf(fmaxf(z, 0.f), (float)(RES - 1));
    xo = x; yo = y; zo = z;
    fo = ((int)rintf(x) * RES + (int)rintf(y)) * RES + (int)rintf(z);
}

// -------- norm coords (output 2), u16 voxel idx, LDS-private counts (u16 partials) --------
// 128 blocks = (batch, chunk of 8192 points) x 1024 threads.
__global__ __launch_bounds__(1024, 1)
void norm_cnt_kernel(const float* __restrict__ coords,
                     const float* __restrict__ sums,
                     const unsigned int* __restrict__ r2bits,
                     float* __restrict__ out_norm,
                     unsigned short* __restrict__ idx16,
                     unsigned short* __restrict__ cnt_part) {
    __shared__ unsigned int lcnt[R3];            // 128 KiB
    const int bid = blockIdx.x;                  // 0..127
    const int b = bid >> 3;
    const int chunk = bid & 7;
    const int tid = threadIdx.x;

    for (int k = tid; k < R3 / 4; k += 1024)
        reinterpret_cast<uint4*>(lcnt)[k] = make_uint4(0u, 0u, 0u, 0u);
    __syncthreads();

    const float mx = sums[b * 3 + 0] * (1.0f / NPTS);
    const float my = sums[b * 3 + 1] * (1.0f / NPTS);
    const float mz = sums[b * 3 + 2] * (1.0f / NPTS);
    const float denom = 2.0f * sqrtf(__uint_as_float(r2bits[b]));

    const float* cb = coords + (size_t)b * 3 * NPTS;
    float* ob = out_norm + (size_t)b * 3 * NPTS;
    unsigned short* ib = idx16 + (size_t)b * NPTS;

    const int base4 = chunk * 2048;
    #pragma unroll
    for (int it = 0; it < 2; ++it) {
        const int n4 = base4 + it * 1024 + tid;
        float4 X = reinterpret_cast<const float4*>(cb)[n4];
        float4 Y = reinterpret_cast<const float4*>(cb + NPTS)[n4];
        float4 Z = reinterpret_cast<const float4*>(cb + 2 * NPTS)[n4];

        float xs[4] = {X.x, X.y, X.z, X.w};
        float ys[4] = {Y.x, Y.y, Y.z, Y.w};
        float zs[4] = {Z.x, Z.y, Z.z, Z.w};
        float xo[4], yo[4], zo[4];
        int fo[4];
        #pragma unroll
        for (int j = 0; j < 4; ++j)
            vox_of(xs[j], ys[j], zs[j], mx, my, mz, denom, xo[j], yo[j], zo[j], fo[j]);
        #pragma unroll
        for (int j = 0; j < 4; ++j) atomicAdd(&lcnt[fo[j]], 1u);

        reinterpret_cast<float4*>(ob)[n4] = make_float4(xo[0], xo[1], xo[2], xo[3]);
        reinterpret_cast<float4*>(ob + NPTS)[n4] = make_float4(yo[0], yo[1], yo[2], yo[3]);
        reinterpret_cast<float4*>(ob + 2 * NPTS)[n4] = make_float4(zo[0], zo[1], zo[2], zo[3]);
        reinterpret_cast<ushort4*>(ib)[n4] = make_ushort4(
            (unsigned short)fo[0], (unsigned short)fo[1],
            (unsigned short)fo[2], (unsigned short)fo[3]);
    }
    __syncthreads();

    // flush LDS counts as u16 partials (max per chunk = 8192, fits)
    unsigned short* pb = cnt_part + (size_t)bid * R3;
    for (int k = tid; k < R3 / 8; k += 1024) {
        const uint4 a = reinterpret_cast<const uint4*>(lcnt)[2 * k];
        const uint4 c = reinterpret_cast<const uint4*>(lcnt)[2 * k + 1];
        reinterpret_cast<uint4*>(pb)[k] = make_uint4(
            (a.x & 0xffffu) | (a.y << 16), (a.z & 0xffffu) | (a.w << 16),
            (c.x & 0xffffu) | (c.y << 16), (c.z & 0xffffu) | (c.w << 16));
    }
}

// ---------------- Scan: cnt_part(u16) -> pre(in-place u16), counts(u32), start(u32) ----------------
// 16 blocks (one per batch) x 1024 threads; thread owns 32 consecutive voxels.
__global__ __launch_bounds__(1024)
void scan_kernel(unsigned short* __restrict__ cnt_part,
                 unsigned int* __restrict__ counts,
                 unsigned int* __restrict__ start) {
    const int b = blockIdx.x;
    const int t = threadIdx.x;
    const int base = t * 32;

    unsigned int c32[32];
    #pragma unroll
    for (int i = 0; i < 32; ++i) c32[i] = 0u;

    for (int p = 0; p < 8; ++p) {
        uint4* rowp = reinterpret_cast<uint4*>(cnt_part + (size_t)(b * 8 + p) * R3 + base);
        unsigned int q[16], wq[16];
        uint4 a0 = rowp[0], a1 = rowp[1], a2 = rowp[2], a3 = rowp[3];
        reinterpret_cast<uint4*>(q)[0] = a0;
        reinterpret_cast<uint4*>(q)[1] = a1;
        reinterpret_cast<uint4*>(q)[2] = a2;
        reinterpret_cast<uint4*>(q)[3] = a3;
        #pragma unroll
        for (int i = 0; i < 16; ++i) {
            wq[i] = (c32[2 * i] & 0xffffu) | (c32[2 * i + 1] << 16);
            c32[2 * i]     += q[i] & 0xffffu;
            c32[2 * i + 1] += q[i] >> 16;
        }
        rowp[0] = reinterpret_cast<uint4*>(wq)[0];
        rowp[1] = reinterpret_cast<uint4*>(wq)[1];
        rowp[2] = reinterpret_cast<uint4*>(wq)[2];
        rowp[3] = reinterpret_cast<uint4*>(wq)[3];
    }

    unsigned int s = 0;
    #pragma unroll
    for (int i = 0; i < 32; ++i) s += c32[i];

    __shared__ unsigned int red[1024];
    red[t] = s;
    __syncthreads();
    for (int off = 1; off < 1024; off <<= 1) {
        unsigned int v = (t >= off) ? red[t - off] : 0u;
        __syncthreads();
        red[t] += v;
        __syncthreads();
    }
    unsigned int run = (t == 0) ? 0u : red[t - 1];

    unsigned int st[32];
    #pragma unroll
    for (int i = 0; i < 32; ++i) { st[i] = run; run += c32[i]; }

    uint4* cdst = reinterpret_cast<uint4*>(counts + (size_t)b * R3 + base);
    uint4* sdst = reinterpret_cast<uint4*>(start + (size_t)b * R3 + base);
    #pragma unroll
    for (int i = 0; i < 8; ++i) {
        cdst[i] = reinterpret_cast<uint4*>(c32)[i];
        sdst[i] = reinterpret_cast<uint4*>(st)[i];
    }
}

// ---------------- Rank: 2-level LDS cursors, no global atomics ----------------
// 128 blocks = (batch, chunk) x 1024 threads. cursor[v] = start[v] + pre[chunk][v].
__global__ __launch_bounds__(1024, 1)
void rank_kernel(const unsigned short* __restrict__ idx16,
                 const unsigned int* __restrict__ start,
                 const unsigned short* __restrict__ pre,
                 unsigned short* __restrict__ rank16) {
    __shared__ unsigned int cursor[R3];          // 128 KiB
    const int bid = blockIdx.x;
    const int b = bid >> 3;
    const int chunk = bid & 7;
    const int tid = threadIdx.x;

    for (int k = tid; k < R3 / 8; k += 1024) {
        const uint4 s0 = reinterpret_cast<const uint4*>(start + (size_t)b * R3)[2 * k];
        const uint4 s1 = reinterpret_cast<const uint4*>(start + (size_t)b * R3)[2 * k + 1];
        const uint4 pr = reinterpret_cast<const uint4*>(pre + (size_t)bid * R3)[k];
        uint4 c0, c1;
        c0.x = s0.x + (pr.x & 0xffffu); c0.y = s0.y + (pr.x >> 16);
        c0.z = s0.z + (pr.y & 0xffffu); c0.w = s0.w + (pr.y >> 16);
        c1.x = s1.x + (pr.z & 0xffffu); c1.y = s1.y + (pr.z >> 16);
        c1.z = s1.z + (pr.w & 0xffffu); c1.w = s1.w + (pr.w >> 16);
        reinterpret_cast<uint4*>(cursor)[2 * k] = c0;
        reinterpret_cast<uint4*>(cursor)[2 * k + 1] = c1;
    }
    __syncthreads();

    const unsigned short* ib = idx16 + (size_t)b * NPTS;
    unsigned short* rb = rank16 + (size_t)b * NPTS;
    const int base4 = chunk * 2048;
    #pragma unroll
    for (int it = 0; it < 2; ++it) {
        const int n4 = base4 + it * 1024 + tid;
        const ushort4 g = reinterpret_cast<const ushort4*>(ib)[n4];
        ushort4 r;
        r.x = (unsigned short)atomicAdd(&cursor[g.x], 1u);
        r.y = (unsigned short)atomicAdd(&cursor[g.y], 1u);
        r.z = (unsigned short)atomicAdd(&cursor[g.z], 1u);
        r.w = (unsigned short)atomicAdd(&cursor[g.w], 1u);
        reinterpret_cast<ushort4*>(rb)[n4] = r;
    }
}

// ---------------- Gather-transpose: ft[b][rank[n]][c] = (half)features[b][c][n] ----------------
__global__ __launch_bounds__(256)
void gt_kernel(const float* __restrict__ features,
               const unsigned short* __restrict__ rank16,
               __half* __restrict__ ft) {
    __shared__ float tile[64][257];
    __shared__ unsigned short rlds[256];
    const int b = blockIdx.y;
    const int n0 = blockIdx.x * 256;
    const int t = threadIdx.x;
    const int w = t >> 6;
    const int lane = t & 63;

    rlds[t] = rank16[(size_t)b * NPTS + n0 + t];

    const float* fb = features + ((size_t)b * CCH) * NPTS + n0;
    for (int c = 0; c < 64; ++c)
        tile[c][t] = fb[(size_t)c * NPTS + t];
    __syncthreads();

    __half* fo = ft + ((size_t)b * NPTS) * CCH;
    for (int jg = 0; jg < 64; ++jg) {
        const int j = jg * 4 + w;
        const int row = (int)rlds[j];
        fo[(size_t)row * CCH + lane] = __float2half_rn(tile[lane][j]);
    }
}

// ---------------- Segmented sum: j-balanced waves over 128-voxel windows ----------------
// grid (R3/WIN, BATCH) x 256 thr. lane = channel. Registers accumulate a run;
// flush via LDS f32 atomic (only wave-split voxels actually contend).
__global__ __launch_bounds__(256)
void seg_kernel(const __half* __restrict__ ft,
                const unsigned int* __restrict__ start,
                const unsigned int* __restrict__ counts,
                float* __restrict__ vox) {
    __shared__ float tile[64][WIN + 1];          // pad: flush banks = (lane+v)&31
    __shared__ unsigned int sw[WIN + 1];
    const int b = blockIdx.y;
    const int v0 = blockIdx.x * WIN;
    const int t = threadIdx.x;
    const int w = t >> 6;
    const int lane = t & 63;

    for (int i = t; i < 64 * (WIN + 1) / 4; i += 256)
        reinterpret_cast<float4*>(&tile[0][0])[i] = make_float4(0.f, 0.f, 0.f, 0.f);
    for (int i = t; i < WIN + 1; i += 256)
        sw[i] = (v0 + i < R3) ? start[(size_t)b * R3 + v0 + i] : (unsigned int)NPTS;
    __syncthreads();

    const unsigned int J0 = sw[0], J1 = sw[WIN];
    const unsigned int len = J1 - J0;
    const unsigned int jb = J0 + ((len * (unsigned)w) >> 2);
    const unsigned int je = J0 + ((len * (unsigned)(w + 1)) >> 2);

    if (jb < je) {
        // largest v with sw[v] <= jb
        int lo = 0, hi = WIN;
        while (hi - lo > 1) {
            const int mid = (lo + hi) >> 1;
            if (sw[mid] <= jb) lo = mid; else hi = mid;
        }
        int v = lo;
        unsigned int nxt = sw[v + 1];
        const __half* fb = ft + ((size_t)b * NPTS) * CCH;
        float acc = 0.f;
        for (unsigned int j = jb; j < je; ++j) {
            while (j >= nxt) {                   // uniform; advances <= WIN total
                if (acc != 0.f) { atomicAdd(&tile[lane][v], acc); acc = 0.f; }
                ++v;
                nxt = sw[v + 1];
            }
            acc += __half2float(fb[(size_t)j * CCH + lane]);
        }
        if (acc != 0.f) atomicAdd(&tile[lane][v], acc);
    }
    __syncthreads();

    const unsigned int* cb = counts + (size_t)b * R3 + v0;
    float* ob = vox + ((size_t)b * CCH) * R3 + v0;
    for (int g = 0; g < 64 * WIN / 256; ++g) {
        const int id = g * 256 + t;
        const int c = id >> 7;                   // WIN = 128
        const int vv = id & (WIN - 1);
        const float cnt = (float)cb[vv];
        ob[(size_t)c * R3 + vv] = tile[c][vv] / fmaxf(cnt, 1.f);
    }
}

// ============================ fallback (atomic) path ============================

__global__ void norm_fb_kernel(const float* __restrict__ coords,
                               const float* __restrict__ sums,
                               const unsigned int* __restrict__ r2bits,
                               float* __restrict__ out_norm,
                               int* __restrict__ idx,
                               unsigned int* __restrict__ counts) {
    const int t = blockIdx.x * blockDim.x + threadIdx.x;
    if (t >= BATCH * NPTS4) return;
    const int b = t >> 14;
    const int n4 = t & (NPTS4 - 1);
    const float mx = sums[b * 3 + 0] * (1.0f / NPTS);
    const float my = sums[b * 3 + 1] * (1.0f / NPTS);
    const float mz = sums[b * 3 + 2] * (1.0f / NPTS);
    const float denom = 2.0f * sqrtf(__uint_as_float(r2bits[b]));
    const float* cb = coords + (size_t)b * 3 * NPTS;
    float4 X = reinterpret_cast<const float4*>(cb)[n4];
    float4 Y = reinterpret_cast<const float4*>(cb + NPTS)[n4];
    float4 Z = reinterpret_cast<const float4*>(cb + 2 * NPTS)[n4];
    float xs[4] = {X.x, X.y, X.z, X.w};
    float ys[4] = {Y.x, Y.y, Y.z, Y.w};
    float zs[4] = {Z.x, Z.y, Z.z, Z.w};
    float xo[4], yo[4], zo[4];
    int fo[4];
    unsigned int* cnt = counts + (size_t)b * R3;
    #pragma unroll
    for (int j = 0; j < 4; ++j)
        vox_of(xs[j], ys[j], zs[j], mx, my, mz, denom, xo[j], yo[j], zo[j], fo[j]);
    #pragma unroll
    for (int j = 0; j < 4; ++j) atomicAdd(&cnt[fo[j]], 1u);
    float* ob = out_norm + (size_t)b * 3 * NPTS;
    reinterpret_cast<float4*>(ob)[n4] = make_float4(xo[0], xo[1], xo[2], xo[3]);
    reinterpret_cast<float4*>(ob + NPTS)[n4] = make_float4(yo[0], yo[1], yo[2], yo[3]);
    reinterpret_cast<float4*>(ob + 2 * NPTS)[n4] = make_float4(zo[0], zo[1], zo[2], zo[3]);
    reinterpret_cast<int4*>(idx + (size_t)b * NPTS)[n4] = make_int4(fo[0], fo[1], fo[2], fo[3]);
}

__device__ __forceinline__ void lds_pk_add_f16(unsigned int addr_off, unsigned int packed) {
    asm volatile("ds_pk_add_f16 %0, %1" :: "v"(addr_off), "v"(packed) : "memory");
}
__device__ __forceinline__ unsigned int pack_rtz(float a, float b) {
    auto p = __builtin_amdgcn_cvt_pkrtz(a, b);
    return __builtin_bit_cast(unsigned int, p);
}

__global__ __launch_bounds__(1024, 1)
void scatter_fb_kernel(const float* __restrict__ features,
                       const int* __restrict__ idx,
                       const unsigned int* __restrict__ counts,
                       float* __restrict__ vox) {
    __shared__ unsigned int acc[R3];
    const int bc2 = blockIdx.x;
    const int b = bc2 >> 5;
    const int c0 = (bc2 & 31) * 2;
    for (int v = threadIdx.x; v < R3 / 4; v += 1024)
        reinterpret_cast<uint4*>(acc)[v] = make_uint4(0u, 0u, 0u, 0u);
    __syncthreads();
    const unsigned int accbase = (unsigned int)(uintptr_t)acc;
    const float4* f0p = reinterpret_cast<const float4*>(features + ((size_t)b * CCH + c0) * NPTS);
    const float4* f1p = reinterpret_cast<const float4*>(features + ((size_t)b * CCH + c0 + 1) * NPTS);
    const int4* i4p = reinterpret_cast<const int4*>(idx + (size_t)b * NPTS);
    for (int g = threadIdx.x; g < NPTS4; g += 1024) {
        const float4 f0 = f0p[g];
        const float4 f1 = f1p[g];
        const int4 i = i4p[g];
        lds_pk_add_f16(accbase + 4u * (unsigned)i.x, pack_rtz(f0.x, f1.x));
        lds_pk_add_f16(accbase + 4u * (unsigned)i.y, pack_rtz(f0.y, f1.y));
        lds_pk_add_f16(accbase + 4u * (unsigned)i.z, pack_rtz(f0.z, f1.z));
        lds_pk_add_f16(accbase + 4u * (unsigned)i.w, pack_rtz(f0.w, f1.w));
    }
    __syncthreads();
    const uint4* c4 = reinterpret_cast<const uint4*>(counts + (size_t)b * R3);
    float* o0 = vox + ((size_t)b * CCH + c0) * R3;
    float* o1 = o0 + R3;
    for (int k = threadIdx.x; k < R3 / 4; k += 1024) {
        const uint4 u = reinterpret_cast<const uint4*>(acc)[k];
        const uint4 c = c4[k];
        const float2 a0 = __half22float2(__builtin_bit_cast(__half2, u.x));
        const float2 a1 = __half22float2(__builtin_bit_cast(__half2, u.y));
        const float2 a2 = __half22float2(__builtin_bit_cast(__half2, u.z));
        const float2 a3 = __half22float2(__builtin_bit_cast(__half2, u.w));
        const float r0 = 1.f / fmaxf((float)c.x, 1.f);
        const float r1 = 1.f / fmaxf((float)c.y, 1.f);
        const float r2 = 1.f / fmaxf((float)c.z, 1.f);
        const float r3 = 1.f / fmaxf((float)c.w, 1.f);
        reinterpret_cast<float4*>(o0)[k] = make_float4(a0.x * r0, a1.x * r1, a2.x * r2, a3.x * r3);
        reinterpret_cast<float4*>(o1)[k] = make_float4(a0.y * r0, a1.y * r1, a2.y * r2, a3.y * r3);
    }
}

// ============================ launch ============================

extern "C" void kernel_launch(void* const* d_in, const int* in_sizes, int n_in,
                              void* d_out, int out_size, void* d_ws, size_t ws_size,
                              hipStream_t stream) {
    const float* features = (const float*)d_in[0];   // [16,64,65536]
    const float* coords   = (const float*)d_in[1];   // [16,3,65536]

    float* vox      = (float*)d_out;                             // 33,554,432 f32
    float* out_norm = (float*)d_out + (size_t)BATCH * CCH * R3;  // 3,145,728 f32

    char* ws = (char*)d_ws;
    float*          sums   = (float*)ws;                     // 192 B
    unsigned int*   r2bits = (unsigned int*)(ws + 192);      // 64 B
    size_t off = 256;
    unsigned short* idx16   = (unsigned short*)(ws + off); off += (size_t)BATCH * NPTS * 2;  // 2 MiB
    unsigned short* cnt_part= (unsigned short*)(ws + off); off += (size_t)128 * R3 * 2;      // 8 MiB
    unsigned int*   counts  = (unsigned int*)(ws + off);   off += (size_t)BATCH * R3 * 4;    // 2 MiB
    unsigned int*   start   = (unsigned int*)(ws + off);   off += (size_t)BATCH * R3 * 4;    // 2 MiB
    unsigned short* rank16  = (unsigned short*)(ws + off); off += (size_t)BATCH * NPTS * 2;  // 2 MiB
    __half*         ft      = (__half*)(ws + off);         off += (size_t)BATCH * NPTS * CCH * 2; // 128 MiB
    const size_t need = off;

    (void)hipMemsetAsync(ws, 0, 256, stream);

    statsA_kernel<<<256, 256, 0, stream>>>(coords, sums);
    statsB_kernel<<<256, 256, 0, stream>>>(coords, sums, r2bits);

    if (ws_size >= need) {
        norm_cnt_kernel<<<128, 1024, 0, stream>>>(coords, sums, r2bits,
                                                  out_norm, idx16, cnt_part);
        scan_kernel<<<BATCH, 1024, 0, stream>>>(cnt_part, counts, start);
        rank_kernel<<<128, 1024, 0, stream>>>(idx16, start, cnt_part, rank16);
        gt_kernel<<<dim3(NPTS / 256, BATCH), 256, 0, stream>>>(features, rank16, ft);
        seg_kernel<<<dim3(R3 / WIN, BATCH), 256, 0, stream>>>(ft, start, counts, vox);
    } else {
        int* idx_fb = (int*)(ws + 256);
        unsigned int* counts_fb = (unsigned int*)(ws + 256 + (size_t)BATCH * NPTS * 4);
        (void)hipMemsetAsync(counts_fb, 0, (size_t)BATCH * R3 * 4, stream);
        norm_fb_kernel<<<BATCH * NPTS4 / 256, 256, 0, stream>>>(
            coords, sums, r2bits, out_norm, idx_fb, counts_fb);
        scatter_fb_kernel<<<BATCH * (CCH / 2), 1024, 0, stream>>>(
            features, idx_fb, counts_fb, vox);
    }
}

// Round 9
// 423.744 us; speedup vs baseline: 1.9809x; 1.9809x over previous
//
#include <hip/hip_runtime.h>
#include <hip/hip_fp16.h>

#define RES 32
#define R3 32768
#define BATCH 16
#define CCH 64
#define NPTS 65536
#define NPTS4 16384
#define WIN 128

// ---------------- Stats phase A: partial coord sums ----------------
__global__ void statsA_kernel(const float* __restrict__ coords,
                              float* __restrict__ sums) {
    const int bid = blockIdx.x;      // 0..255
    const int b = bid >> 4;
    const int chunk = bid & 15;
    const int tid = threadIdx.x;     // 0..255
    const float* cb = coords + (size_t)b * 3 * NPTS;
    const int base4 = chunk * 1024;

    float sx = 0.f, sy = 0.f, sz = 0.f;
    for (int k = tid; k < 1024; k += 256) {
        float4 x4 = reinterpret_cast<const float4*>(cb)[base4 + k];
        float4 y4 = reinterpret_cast<const float4*>(cb + NPTS)[base4 + k];
        float4 z4 = reinterpret_cast<const float4*>(cb + 2 * NPTS)[base4 + k];
        sx += (x4.x + x4.y) + (x4.z + x4.w);
        sy += (y4.x + y4.y) + (y4.z + y4.w);
        sz += (z4.x + z4.y) + (z4.z + z4.w);
    }
    __shared__ float red[3][256];
    red[0][tid] = sx; red[1][tid] = sy; red[2][tid] = sz;
    __syncthreads();
    for (int s = 128; s > 0; s >>= 1) {
        if (tid < s) {
            red[0][tid] += red[0][tid + s];
            red[1][tid] += red[1][tid + s];
            red[2][tid] += red[2][tid + s];
        }
        __syncthreads();
    }
    if (tid == 0) {
        atomicAdd(&sums[b * 3 + 0], red[0][0]);
        atomicAdd(&sums[b * 3 + 1], red[1][0]);
        atomicAdd(&sums[b * 3 + 2], red[2][0]);
    }
}

// ---------------- Stats phase B: max squared radius ----------------
__global__ void statsB_kernel(const float* __restrict__ coords,
                              const float* __restrict__ sums,
                              unsigned int* __restrict__ r2bits) {
    const int bid = blockIdx.x;
    const int b = bid >> 4;
    const int chunk = bid & 15;
    const int tid = threadIdx.x;
    const float mx = sums[b * 3 + 0] * (1.0f / NPTS);
    const float my = sums[b * 3 + 1] * (1.0f / NPTS);
    const float mz = sums[b * 3 + 2] * (1.0f / NPTS);
    const float* cb = coords + (size_t)b * 3 * NPTS;
    const int base4 = chunk * 1024;

    float m = 0.f;
    for (int k = tid; k < 1024; k += 256) {
        float4 x4 = reinterpret_cast<const float4*>(cb)[base4 + k];
        float4 y4 = reinterpret_cast<const float4*>(cb + NPTS)[base4 + k];
        float4 z4 = reinterpret_cast<const float4*>(cb + 2 * NPTS)[base4 + k];
        float dx, dy, dz, r2;
        dx = x4.x - mx; dy = y4.x - my; dz = z4.x - mz; r2 = dx*dx + dy*dy + dz*dz; m = fmaxf(m, r2);
        dx = x4.y - mx; dy = y4.y - my; dz = z4.y - mz; r2 = dx*dx + dy*dy + dz*dz; m = fmaxf(m, r2);
        dx = x4.z - mx; dy = y4.z - my; dz = z4.z - mz; r2 = dx*dx + dy*dy + dz*dz; m = fmaxf(m, r2);
        dx = x4.w - mx; dy = y4.w - my; dz = z4.w - mz; r2 = dx*dx + dy*dy + dz*dz; m = fmaxf(m, r2);
    }
    __shared__ float red[256];
    red[tid] = m;
    __syncthreads();
    for (int s = 128; s > 0; s >>= 1) {
        if (tid < s) red[tid] = fmaxf(red[tid], red[tid + s]);
        __syncthreads();
    }
    if (tid == 0)
        atomicMax(&r2bits[b], __float_as_uint(red[0]));
}

// shared voxelization math
__device__ __forceinline__ void vox_of(float xs, float ys, float zs,
                                       float mx, float my, float mz, float denom,
                                       float& xo, float& yo, float& zo, int& fo) {
    float x = ((xs - mx) / denom + 0.5f) * (float)RES;
    float y = ((ys - my) / denom + 0.5f) * (float)RES;
    float z = ((zs - mz) / denom + 0.5f) * (float)RES;
    x = fminf(fmaxf(x, 0.f), (float)(RES - 1));
    y = fminf(fmaxf(y, 0.f), (float)(RES - 1));
    z = fminf(fmaxf(z, 0.f), (float)(RES - 1));
    xo = x; yo = y; zo = z;
    fo = ((int)rintf(x) * RES + (int)rintf(y)) * RES + (int)rintf(z);
}

// -------- norm coords (output 2), u16 voxel idx, LDS-private counts (u16 partials) --------
__global__ __launch_bounds__(1024, 1)
void norm_cnt_kernel(const float* __restrict__ coords,
                     const float* __restrict__ sums,
                     const unsigned int* __restrict__ r2bits,
                     float* __restrict__ out_norm,
                     unsigned short* __restrict__ idx16,
                     unsigned short* __restrict__ cnt_part) {
    __shared__ unsigned int lcnt[R3];            // 128 KiB
    const int bid = blockIdx.x;                  // 0..127
    const int b = bid >> 3;
    const int chunk = bid & 7;
    const int tid = threadIdx.x;

    for (int k = tid; k < R3 / 4; k += 1024)
        reinterpret_cast<uint4*>(lcnt)[k] = make_uint4(0u, 0u, 0u, 0u);
    __syncthreads();

    const float mx = sums[b * 3 + 0] * (1.0f / NPTS);
    const float my = sums[b * 3 + 1] * (1.0f / NPTS);
    const float mz = sums[b * 3 + 2] * (1.0f / NPTS);
    const float denom = 2.0f * sqrtf(__uint_as_float(r2bits[b]));

    const float* cb = coords + (size_t)b * 3 * NPTS;
    float* ob = out_norm + (size_t)b * 3 * NPTS;
    unsigned short* ib = idx16 + (size_t)b * NPTS;

    const int base4 = chunk * 2048;
    #pragma unroll
    for (int it = 0; it < 2; ++it) {
        const int n4 = base4 + it * 1024 + tid;
        float4 X = reinterpret_cast<const float4*>(cb)[n4];
        float4 Y = reinterpret_cast<const float4*>(cb + NPTS)[n4];
        float4 Z = reinterpret_cast<const float4*>(cb + 2 * NPTS)[n4];

        float xs[4] = {X.x, X.y, X.z, X.w};
        float ys[4] = {Y.x, Y.y, Y.z, Y.w};
        float zs[4] = {Z.x, Z.y, Z.z, Z.w};
        float xo[4], yo[4], zo[4];
        int fo[4];
        #pragma unroll
        for (int j = 0; j < 4; ++j)
            vox_of(xs[j], ys[j], zs[j], mx, my, mz, denom, xo[j], yo[j], zo[j], fo[j]);
        #pragma unroll
        for (int j = 0; j < 4; ++j) atomicAdd(&lcnt[fo[j]], 1u);

        reinterpret_cast<float4*>(ob)[n4] = make_float4(xo[0], xo[1], xo[2], xo[3]);
        reinterpret_cast<float4*>(ob + NPTS)[n4] = make_float4(yo[0], yo[1], yo[2], yo[3]);
        reinterpret_cast<float4*>(ob + 2 * NPTS)[n4] = make_float4(zo[0], zo[1], zo[2], zo[3]);
        reinterpret_cast<ushort4*>(ib)[n4] = make_ushort4(
            (unsigned short)fo[0], (unsigned short)fo[1],
            (unsigned short)fo[2], (unsigned short)fo[3]);
    }
    __syncthreads();

    unsigned short* pb = cnt_part + (size_t)bid * R3;
    for (int k = tid; k < R3 / 8; k += 1024) {
        const uint4 a = reinterpret_cast<const uint4*>(lcnt)[2 * k];
        const uint4 c = reinterpret_cast<const uint4*>(lcnt)[2 * k + 1];
        reinterpret_cast<uint4*>(pb)[k] = make_uint4(
            (a.x & 0xffffu) | (a.y << 16), (a.z & 0xffffu) | (a.w << 16),
            (c.x & 0xffffu) | (c.y << 16), (c.z & 0xffffu) | (c.w << 16));
    }
}

// ---------------- Scan: cnt_part(u16) -> pre(in-place u16), counts(u32), start(u32) ----------------
__global__ __launch_bounds__(1024)
void scan_kernel(unsigned short* __restrict__ cnt_part,
                 unsigned int* __restrict__ counts,
                 unsigned int* __restrict__ start) {
    const int b = blockIdx.x;
    const int t = threadIdx.x;
    const int base = t * 32;

    unsigned int c32[32];
    #pragma unroll
    for (int i = 0; i < 32; ++i) c32[i] = 0u;

    for (int p = 0; p < 8; ++p) {
        uint4* rowp = reinterpret_cast<uint4*>(cnt_part + (size_t)(b * 8 + p) * R3 + base);
        unsigned int q[16], wq[16];
        uint4 a0 = rowp[0], a1 = rowp[1], a2 = rowp[2], a3 = rowp[3];
        reinterpret_cast<uint4*>(q)[0] = a0;
        reinterpret_cast<uint4*>(q)[1] = a1;
        reinterpret_cast<uint4*>(q)[2] = a2;
        reinterpret_cast<uint4*>(q)[3] = a3;
        #pragma unroll
        for (int i = 0; i < 16; ++i) {
            wq[i] = (c32[2 * i] & 0xffffu) | (c32[2 * i + 1] << 16);
            c32[2 * i]     += q[i] & 0xffffu;
            c32[2 * i + 1] += q[i] >> 16;
        }
        rowp[0] = reinterpret_cast<uint4*>(wq)[0];
        rowp[1] = reinterpret_cast<uint4*>(wq)[1];
        rowp[2] = reinterpret_cast<uint4*>(wq)[2];
        rowp[3] = reinterpret_cast<uint4*>(wq)[3];
    }

    unsigned int s = 0;
    #pragma unroll
    for (int i = 0; i < 32; ++i) s += c32[i];

    __shared__ unsigned int red[1024];
    red[t] = s;
    __syncthreads();
    for (int off = 1; off < 1024; off <<= 1) {
        unsigned int v = (t >= off) ? red[t - off] : 0u;
        __syncthreads();
        red[t] += v;
        __syncthreads();
    }
    unsigned int run = (t == 0) ? 0u : red[t - 1];

    unsigned int st[32];
    #pragma unroll
    for (int i = 0; i < 32; ++i) { st[i] = run; run += c32[i]; }

    uint4* cdst = reinterpret_cast<uint4*>(counts + (size_t)b * R3 + base);
    uint4* sdst = reinterpret_cast<uint4*>(start + (size_t)b * R3 + base);
    #pragma unroll
    for (int i = 0; i < 8; ++i) {
        cdst[i] = reinterpret_cast<uint4*>(c32)[i];
        sdst[i] = reinterpret_cast<uint4*>(st)[i];
    }
}

// ---------------- Rank: 2-level LDS cursors, no global atomics ----------------
__global__ __launch_bounds__(1024, 1)
void rank_kernel(const unsigned short* __restrict__ idx16,
                 const unsigned int* __restrict__ start,
                 const unsigned short* __restrict__ pre,
                 unsigned short* __restrict__ rank16) {
    __shared__ unsigned int cursor[R3];          // 128 KiB
    const int bid = blockIdx.x;
    const int b = bid >> 3;
    const int chunk = bid & 7;
    const int tid = threadIdx.x;

    for (int k = tid; k < R3 / 8; k += 1024) {
        const uint4 s0 = reinterpret_cast<const uint4*>(start + (size_t)b * R3)[2 * k];
        const uint4 s1 = reinterpret_cast<const uint4*>(start + (size_t)b * R3)[2 * k + 1];
        const uint4 pr = reinterpret_cast<const uint4*>(pre + (size_t)bid * R3)[k];
        uint4 c0, c1;
        c0.x = s0.x + (pr.x & 0xffffu); c0.y = s0.y + (pr.x >> 16);
        c0.z = s0.z + (pr.y & 0xffffu); c0.w = s0.w + (pr.y >> 16);
        c1.x = s1.x + (pr.z & 0xffffu); c1.y = s1.y + (pr.z >> 16);
        c1.z = s1.z + (pr.w & 0xffffu); c1.w = s1.w + (pr.w >> 16);
        reinterpret_cast<uint4*>(cursor)[2 * k] = c0;
        reinterpret_cast<uint4*>(cursor)[2 * k + 1] = c1;
    }
    __syncthreads();

    const unsigned short* ib = idx16 + (size_t)b * NPTS;
    unsigned short* rb = rank16 + (size_t)b * NPTS;
    const int base4 = chunk * 2048;
    #pragma unroll
    for (int it = 0; it < 2; ++it) {
        const int n4 = base4 + it * 1024 + tid;
        const ushort4 g = reinterpret_cast<const ushort4*>(ib)[n4];
        ushort4 r;
        r.x = (unsigned short)atomicAdd(&cursor[g.x], 1u);
        r.y = (unsigned short)atomicAdd(&cursor[g.y], 1u);
        r.z = (unsigned short)atomicAdd(&cursor[g.z], 1u);
        r.w = (unsigned short)atomicAdd(&cursor[g.w], 1u);
        reinterpret_cast<ushort4*>(rb)[n4] = r;
    }
}

// ---------------- Gather-transpose: ft[b][rank[n]][c] = (half)features[b][c][n] ----------------
__global__ __launch_bounds__(256)
void gt_kernel(const float* __restrict__ features,
               const unsigned short* __restrict__ rank16,
               __half* __restrict__ ft) {
    __shared__ float tile[64][257];
    __shared__ unsigned short rlds[256];
    const int b = blockIdx.y;
    const int n0 = blockIdx.x * 256;
    const int t = threadIdx.x;
    const int w = t >> 6;
    const int lane = t & 63;

    rlds[t] = rank16[(size_t)b * NPTS + n0 + t];

    const float* fb = features + ((size_t)b * CCH) * NPTS + n0;
    for (int c = 0; c < 64; ++c)
        tile[c][t] = fb[(size_t)c * NPTS + t];
    __syncthreads();

    __half* fo = ft + ((size_t)b * NPTS) * CCH;
    for (int jg = 0; jg < 64; ++jg) {
        const int j = jg * 4 + w;
        const int row = (int)rlds[j];
        fo[(size_t)row * CCH + lane] = __float2half_rn(tile[lane][j]);
    }
}

// ---------------- Segmented sum: counted vectorized per-voxel loops ----------------
// grid (R3/WIN, BATCH) x 256 thr. Wave w owns voxels v = w, w+4, ... (interleave
// balances z-dense centers). Per load-instr: 4 rows x 16 channel-groups = 512B
// coalesced. Reduce via shfl_xor(16,32); lanes 0-15 write float4 exclusively.
__global__ __launch_bounds__(256)
void seg_kernel(const __half* __restrict__ ft,
                const unsigned int* __restrict__ start,
                const unsigned int* __restrict__ counts,
                float* __restrict__ vox) {
    __shared__ float tile[WIN][68];              // 34.8 KiB; [v][c], 16B-aligned rows
    __shared__ unsigned int sw[WIN + 1];
    const int b = blockIdx.y;
    const int v0 = blockIdx.x * WIN;
    const int t = threadIdx.x;
    const int w = t >> 6;
    const int lane = t & 63;
    const int rg = lane >> 4;                    // row-group 0..3
    const int cg = lane & 15;                    // channels 4cg..4cg+3

    for (int i = t; i < WIN + 1; i += 256)
        sw[i] = (v0 + i < R3) ? start[(size_t)b * R3 + v0 + i] : (unsigned int)NPTS;
    __syncthreads();

    const __half* fb = ft + ((size_t)b * NPTS) * CCH;

    for (int v = w; v < WIN; v += 4) {
        const unsigned int js = sw[v], je = sw[v + 1];
        float ax = 0.f, ay = 0.f, az = 0.f, aw = 0.f;
        for (unsigned int r0 = js; r0 < je; r0 += 4) {
            const unsigned int r = r0 + (unsigned)rg;
            if (r < je) {
                const uint2 u = *reinterpret_cast<const uint2*>(
                    fb + (size_t)r * CCH + cg * 4);
                const float2 lo = __half22float2(__builtin_bit_cast(__half2, u.x));
                const float2 hi = __half22float2(__builtin_bit_cast(__half2, u.y));
                ax += lo.x; ay += lo.y; az += hi.x; aw += hi.y;
            }
        }
        ax += __shfl_xor(ax, 16); ay += __shfl_xor(ay, 16);
        az += __shfl_xor(az, 16); aw += __shfl_xor(aw, 16);
        ax += __shfl_xor(ax, 32); ay += __shfl_xor(ay, 32);
        az += __shfl_xor(az, 32); aw += __shfl_xor(aw, 32);
        if (rg == 0 && lane < 16)
            *reinterpret_cast<float4*>(&tile[v][cg * 4]) = make_float4(ax, ay, az, aw);
    }
    __syncthreads();

    const unsigned int* cb = counts + (size_t)b * R3 + v0;
    float* ob = vox + ((size_t)b * CCH) * R3 + v0;
    for (int g = 0; g < 64 * WIN / 256; ++g) {
        const int id = g * 256 + t;
        const int c = id >> 7;                   // WIN = 128
        const int vv = id & (WIN - 1);
        ob[(size_t)c * R3 + vv] = tile[vv][c] / fmaxf((float)cb[vv], 1.f);
    }
}

// ============================ fallback (atomic) path ============================

__global__ void norm_fb_kernel(const float* __restrict__ coords,
                               const float* __restrict__ sums,
                               const unsigned int* __restrict__ r2bits,
                               float* __restrict__ out_norm,
                               int* __restrict__ idx,
                               unsigned int* __restrict__ counts) {
    const int t = blockIdx.x * blockDim.x + threadIdx.x;
    if (t >= BATCH * NPTS4) return;
    const int b = t >> 14;
    const int n4 = t & (NPTS4 - 1);
    const float mx = sums[b * 3 + 0] * (1.0f / NPTS);
    const float my = sums[b * 3 + 1] * (1.0f / NPTS);
    const float mz = sums[b * 3 + 2] * (1.0f / NPTS);
    const float denom = 2.0f * sqrtf(__uint_as_float(r2bits[b]));
    const float* cb = coords + (size_t)b * 3 * NPTS;
    float4 X = reinterpret_cast<const float4*>(cb)[n4];
    float4 Y = reinterpret_cast<const float4*>(cb + NPTS)[n4];
    float4 Z = reinterpret_cast<const float4*>(cb + 2 * NPTS)[n4];
    float xs[4] = {X.x, X.y, X.z, X.w};
    float ys[4] = {Y.x, Y.y, Y.z, Y.w};
    float zs[4] = {Z.x, Z.y, Z.z, Z.w};
    float xo[4], yo[4], zo[4];
    int fo[4];
    unsigned int* cnt = counts + (size_t)b * R3;
    #pragma unroll
    for (int j = 0; j < 4; ++j)
        vox_of(xs[j], ys[j], zs[j], mx, my, mz, denom, xo[j], yo[j], zo[j], fo[j]);
    #pragma unroll
    for (int j = 0; j < 4; ++j) atomicAdd(&cnt[fo[j]], 1u);
    float* ob = out_norm + (size_t)b * 3 * NPTS;
    reinterpret_cast<float4*>(ob)[n4] = make_float4(xo[0], xo[1], xo[2], xo[3]);
    reinterpret_cast<float4*>(ob + NPTS)[n4] = make_float4(yo[0], yo[1], yo[2], yo[3]);
    reinterpret_cast<float4*>(ob + 2 * NPTS)[n4] = make_float4(zo[0], zo[1], zo[2], zo[3]);
    reinterpret_cast<int4*>(idx + (size_t)b * NPTS)[n4] = make_int4(fo[0], fo[1], fo[2], fo[3]);
}

__device__ __forceinline__ void lds_pk_add_f16(unsigned int addr_off, unsigned int packed) {
    asm volatile("ds_pk_add_f16 %0, %1" :: "v"(addr_off), "v"(packed) : "memory");
}
__device__ __forceinline__ unsigned int pack_rtz(float a, float b) {
    auto p = __builtin_amdgcn_cvt_pkrtz(a, b);
    return __builtin_bit_cast(unsigned int, p);
}

__global__ __launch_bounds__(1024, 1)
void scatter_fb_kernel(const float* __restrict__ features,
                       const int* __restrict__ idx,
                       const unsigned int* __restrict__ counts,
                       float* __restrict__ vox) {
    __shared__ unsigned int acc[R3];
    const int bc2 = blockIdx.x;
    const int b = bc2 >> 5;
    const int c0 = (bc2 & 31) * 2;
    for (int v = threadIdx.x; v < R3 / 4; v += 1024)
        reinterpret_cast<uint4*>(acc)[v] = make_uint4(0u, 0u, 0u, 0u);
    __syncthreads();
    const unsigned int accbase = (unsigned int)(uintptr_t)acc;
    const float4* f0p = reinterpret_cast<const float4*>(features + ((size_t)b * CCH + c0) * NPTS);
    const float4* f1p = reinterpret_cast<const float4*>(features + ((size_t)b * CCH + c0 + 1) * NPTS);
    const int4* i4p = reinterpret_cast<const int4*>(idx + (size_t)b * NPTS);
    for (int g = threadIdx.x; g < NPTS4; g += 1024) {
        const float4 f0 = f0p[g];
        const float4 f1 = f1p[g];
        const int4 i = i4p[g];
        lds_pk_add_f16(accbase + 4u * (unsigned)i.x, pack_rtz(f0.x, f1.x));
        lds_pk_add_f16(accbase + 4u * (unsigned)i.y, pack_rtz(f0.y, f1.y));
        lds_pk_add_f16(accbase + 4u * (unsigned)i.z, pack_rtz(f0.z, f1.z));
        lds_pk_add_f16(accbase + 4u * (unsigned)i.w, pack_rtz(f0.w, f1.w));
    }
    __syncthreads();
    const uint4* c4 = reinterpret_cast<const uint4*>(counts + (size_t)b * R3);
    float* o0 = vox + ((size_t)b * CCH + c0) * R3;
    float* o1 = o0 + R3;
    for (int k = threadIdx.x; k < R3 / 4; k += 1024) {
        const uint4 u = reinterpret_cast<const uint4*>(acc)[k];
        const uint4 c = c4[k];
        const float2 a0 = __half22float2(__builtin_bit_cast(__half2, u.x));
        const float2 a1 = __half22float2(__builtin_bit_cast(__half2, u.y));
        const float2 a2 = __half22float2(__builtin_bit_cast(__half2, u.z));
        const float2 a3 = __half22float2(__builtin_bit_cast(__half2, u.w));
        const float r0 = 1.f / fmaxf((float)c.x, 1.f);
        const float r1 = 1.f / fmaxf((float)c.y, 1.f);
        const float r2 = 1.f / fmaxf((float)c.z, 1.f);
        const float r3 = 1.f / fmaxf((float)c.w, 1.f);
        reinterpret_cast<float4*>(o0)[k] = make_float4(a0.x * r0, a1.x * r1, a2.x * r2, a3.x * r3);
        reinterpret_cast<float4*>(o1)[k] = make_float4(a0.y * r0, a1.y * r1, a2.y * r2, a3.y * r3);
    }
}

// ============================ launch ============================

extern "C" void kernel_launch(void* const* d_in, const int* in_sizes, int n_in,
                              void* d_out, int out_size, void* d_ws, size_t ws_size,
                              hipStream_t stream) {
    const float* features = (const float*)d_in[0];   // [16,64,65536]
    const float* coords   = (const float*)d_in[1];   // [16,3,65536]

    float* vox      = (float*)d_out;                             // 33,554,432 f32
    float* out_norm = (float*)d_out + (size_t)BATCH * CCH * R3;  // 3,145,728 f32

    char* ws = (char*)d_ws;
    float*          sums   = (float*)ws;                     // 192 B
    unsigned int*   r2bits = (unsigned int*)(ws + 192);      // 64 B
    size_t off = 256;
    unsigned short* idx16   = (unsigned short*)(ws + off); off += (size_t)BATCH * NPTS * 2;  // 2 MiB
    unsigned short* cnt_part= (unsigned short*)(ws + off); off += (size_t)128 * R3 * 2;      // 8 MiB
    unsigned int*   counts  = (unsigned int*)(ws + off);   off += (size_t)BATCH * R3 * 4;    // 2 MiB
    unsigned int*   start   = (unsigned int*)(ws + off);   off += (size_t)BATCH * R3 * 4;    // 2 MiB
    unsigned short* rank16  = (unsigned short*)(ws + off); off += (size_t)BATCH * NPTS * 2;  // 2 MiB
    __half*         ft      = (__half*)(ws + off);         off += (size_t)BATCH * NPTS * CCH * 2; // 128 MiB
    const size_t need = off;

    (void)hipMemsetAsync(ws, 0, 256, stream);

    statsA_kernel<<<256, 256, 0, stream>>>(coords, sums);
    statsB_kernel<<<256, 256, 0, stream>>>(coords, sums, r2bits);

    if (ws_size >= need) {
        norm_cnt_kernel<<<128, 1024, 0, stream>>>(coords, sums, r2bits,
                                                  out_norm, idx16, cnt_part);
        scan_kernel<<<BATCH, 1024, 0, stream>>>(cnt_part, counts, start);
        rank_kernel<<<128, 1024, 0, stream>>>(idx16, start, cnt_part, rank16);
        gt_kernel<<<dim3(NPTS / 256, BATCH), 256, 0, stream>>>(features, rank16, ft);
        seg_kernel<<<dim3(R3 / WIN, BATCH), 256, 0, stream>>>(ft, start, counts, vox);
    } else {
        int* idx_fb = (int*)(ws + 256);
        unsigned int* counts_fb = (unsigned int*)(ws + 256 + (size_t)BATCH * NPTS * 4);
        (void)hipMemsetAsync(counts_fb, 0, (size_t)BATCH * R3 * 4, stream);
        norm_fb_kernel<<<BATCH * NPTS4 / 256, 256, 0, stream>>>(
            coords, sums, r2bits, out_norm, idx_fb, counts_fb);
        scatter_fb_kernel<<<BATCH * (CCH / 2), 1024, 0, stream>>>(
            features, idx_fb, counts_fb, vox);
    }
}

// Round 10
// 229.049 us; speedup vs baseline: 3.6647x; 1.8500x over previous
//
#include <hip/hip_runtime.h>
#include <hip/hip_fp16.h>

#define RES 32
#define R3 32768
#define BATCH 16
#define CCH 64
#define NPTS 65536
#define NPTS4 16384

// Packed f16 LDS atomic add: ds_pk_add_f16 (non-returning).
__device__ __forceinline__ void lds_pk_add_f16(unsigned int addr_off, unsigned int packed) {
    asm volatile("ds_pk_add_f16 %0, %1" :: "v"(addr_off), "v"(packed) : "memory");
}

__device__ __forceinline__ unsigned int pack_rtz(float a, float b) {
    auto p = __builtin_amdgcn_cvt_pkrtz(a, b);   // __fp16 ext_vector(2)
    return __builtin_bit_cast(unsigned int, p);
}

// ---------------- Stats phase A: partial coord sums ----------------
__global__ void statsA_kernel(const float* __restrict__ coords,
                              float* __restrict__ sums) {
    const int bid = blockIdx.x;      // 0..255
    const int b = bid >> 4;
    const int chunk = bid & 15;
    const int tid = threadIdx.x;     // 0..255
    const float* cb = coords + (size_t)b * 3 * NPTS;
    const int base4 = chunk * 1024;

    float sx = 0.f, sy = 0.f, sz = 0.f;
    for (int k = tid; k < 1024; k += 256) {
        float4 x4 = reinterpret_cast<const float4*>(cb)[base4 + k];
        float4 y4 = reinterpret_cast<const float4*>(cb + NPTS)[base4 + k];
        float4 z4 = reinterpret_cast<const float4*>(cb + 2 * NPTS)[base4 + k];
        sx += (x4.x + x4.y) + (x4.z + x4.w);
        sy += (y4.x + y4.y) + (y4.z + y4.w);
        sz += (z4.x + z4.y) + (z4.z + z4.w);
    }
    __shared__ float red[3][256];
    red[0][tid] = sx; red[1][tid] = sy; red[2][tid] = sz;
    __syncthreads();
    for (int s = 128; s > 0; s >>= 1) {
        if (tid < s) {
            red[0][tid] += red[0][tid + s];
            red[1][tid] += red[1][tid + s];
            red[2][tid] += red[2][tid + s];
        }
        __syncthreads();
    }
    if (tid == 0) {
        atomicAdd(&sums[b * 3 + 0], red[0][0]);
        atomicAdd(&sums[b * 3 + 1], red[1][0]);
        atomicAdd(&sums[b * 3 + 2], red[2][0]);
    }
}

// ---------------- Stats phase B: max squared radius ----------------
__global__ void statsB_kernel(const float* __restrict__ coords,
                              const float* __restrict__ sums,
                              unsigned int* __restrict__ r2bits) {
    const int bid = blockIdx.x;
    const int b = bid >> 4;
    const int chunk = bid & 15;
    const int tid = threadIdx.x;
    const float mx = sums[b * 3 + 0] * (1.0f / NPTS);
    const float my = sums[b * 3 + 1] * (1.0f / NPTS);
    const float mz = sums[b * 3 + 2] * (1.0f / NPTS);
    const float* cb = coords + (size_t)b * 3 * NPTS;
    const int base4 = chunk * 1024;

    float m = 0.f;
    for (int k = tid; k < 1024; k += 256) {
        float4 x4 = reinterpret_cast<const float4*>(cb)[base4 + k];
        float4 y4 = reinterpret_cast<const float4*>(cb + NPTS)[base4 + k];
        float4 z4 = reinterpret_cast<const float4*>(cb + 2 * NPTS)[base4 + k];
        float dx, dy, dz, r2;
        dx = x4.x - mx; dy = y4.x - my; dz = z4.x - mz; r2 = dx*dx + dy*dy + dz*dz; m = fmaxf(m, r2);
        dx = x4.y - mx; dy = y4.y - my; dz = z4.y - mz; r2 = dx*dx + dy*dy + dz*dz; m = fmaxf(m, r2);
        dx = x4.z - mx; dy = y4.z - my; dz = z4.z - mz; r2 = dx*dx + dy*dy + dz*dz; m = fmaxf(m, r2);
        dx = x4.w - mx; dy = y4.w - my; dz = z4.w - mz; r2 = dx*dx + dy*dy + dz*dz; m = fmaxf(m, r2);
    }
    __shared__ float red[256];
    red[tid] = m;
    __syncthreads();
    for (int s = 128; s > 0; s >>= 1) {
        if (tid < s) red[tid] = fmaxf(red[tid], red[tid + s]);
        __syncthreads();
    }
    if (tid == 0)
        atomicMax(&r2bits[b], __float_as_uint(red[0]));  // r2 >= 0: bit order = float order
}

// -------- norm coords (output 2), voxel idx, LDS-private counts (u16 partials) --------
// 128 blocks = (batch, chunk of 8192 points) x 1024 threads; no global atomics.
__global__ __launch_bounds__(1024, 1)
void norm_cnt_kernel(const float* __restrict__ coords,
                     const float* __restrict__ sums,
                     const unsigned int* __restrict__ r2bits,
                     float* __restrict__ out_norm,
                     int* __restrict__ idx,
                     unsigned short* __restrict__ cnt_part) {
    __shared__ unsigned int lcnt[R3];            // 128 KiB
    const int bid = blockIdx.x;                  // 0..127
    const int b = bid >> 3;
    const int chunk = bid & 7;
    const int tid = threadIdx.x;

    for (int k = tid; k < R3 / 4; k += 1024)
        reinterpret_cast<uint4*>(lcnt)[k] = make_uint4(0u, 0u, 0u, 0u);
    __syncthreads();

    const float mx = sums[b * 3 + 0] * (1.0f / NPTS);
    const float my = sums[b * 3 + 1] * (1.0f / NPTS);
    const float mz = sums[b * 3 + 2] * (1.0f / NPTS);
    const float denom = 2.0f * sqrtf(__uint_as_float(r2bits[b]));

    const float* cb = coords + (size_t)b * 3 * NPTS;
    float* ob = out_norm + (size_t)b * 3 * NPTS;
    int* ib = idx + (size_t)b * NPTS;

    const int base4 = chunk * 2048;              // 2048 float4-groups per chunk
    #pragma unroll
    for (int it = 0; it < 2; ++it) {
        const int n4 = base4 + it * 1024 + tid;
        float4 X = reinterpret_cast<const float4*>(cb)[n4];
        float4 Y = reinterpret_cast<const float4*>(cb + NPTS)[n4];
        float4 Z = reinterpret_cast<const float4*>(cb + 2 * NPTS)[n4];

        float xs[4] = {X.x, X.y, X.z, X.w};
        float ys[4] = {Y.x, Y.y, Y.z, Y.w};
        float zs[4] = {Z.x, Z.y, Z.z, Z.w};
        float xo[4], yo[4], zo[4];
        int fo[4];
        #pragma unroll
        for (int j = 0; j < 4; ++j) {
            float x = ((xs[j] - mx) / denom + 0.5f) * (float)RES;
            float y = ((ys[j] - my) / denom + 0.5f) * (float)RES;
            float z = ((zs[j] - mz) / denom + 0.5f) * (float)RES;
            x = fminf(fmaxf(x, 0.f), (float)(RES - 1));
            y = fminf(fmaxf(y, 0.f), (float)(RES - 1));
            z = fminf(fmaxf(z, 0.f), (float)(RES - 1));
            xo[j] = x; yo[j] = y; zo[j] = z;
            fo[j] = ((int)rintf(x) * RES + (int)rintf(y)) * RES + (int)rintf(z);
        }
        #pragma unroll
        for (int j = 0; j < 4; ++j) atomicAdd(&lcnt[fo[j]], 1u);

        reinterpret_cast<float4*>(ob)[n4] = make_float4(xo[0], xo[1], xo[2], xo[3]);
        reinterpret_cast<float4*>(ob + NPTS)[n4] = make_float4(yo[0], yo[1], yo[2], yo[3]);
        reinterpret_cast<float4*>(ob + 2 * NPTS)[n4] = make_float4(zo[0], zo[1], zo[2], zo[3]);
        reinterpret_cast<int4*>(ib)[n4] = make_int4(fo[0], fo[1], fo[2], fo[3]);
    }
    __syncthreads();

    // flush LDS counts as u16 partials (max per chunk = 8192, fits u16)
    unsigned short* pb = cnt_part + (size_t)bid * R3;
    for (int k = tid; k < R3 / 8; k += 1024) {
        const uint4 a = reinterpret_cast<const uint4*>(lcnt)[2 * k];
        const uint4 c = reinterpret_cast<const uint4*>(lcnt)[2 * k + 1];
        reinterpret_cast<uint4*>(pb)[k] = make_uint4(
            (a.x & 0xffffu) | (a.y << 16), (a.z & 0xffffu) | (a.w << 16),
            (c.x & 0xffffu) | (c.y << 16), (c.z & 0xffffu) | (c.w << 16));
    }
}

// ---------------- Reduce 8 u16 partials per batch -> u32 counts ----------------
__global__ void reduce_counts_kernel(const unsigned short* __restrict__ cnt_part,
                                     unsigned int* __restrict__ counts) {
    const int t = blockIdx.x * 256 + threadIdx.x;   // uint4 index over [16][4096]
    const int b = t >> 12;
    const int k = t & 4095;                         // 8 voxels per uint4 of u16

    unsigned int s[8];
    #pragma unroll
    for (int i = 0; i < 8; ++i) s[i] = 0u;

    #pragma unroll
    for (int p = 0; p < 8; ++p) {
        const uint4 u = reinterpret_cast<const uint4*>(
            cnt_part + (size_t)(b * 8 + p) * R3)[k];
        s[0] += u.x & 0xffffu; s[1] += u.x >> 16;
        s[2] += u.y & 0xffffu; s[3] += u.y >> 16;
        s[4] += u.z & 0xffffu; s[5] += u.z >> 16;
        s[6] += u.w & 0xffffu; s[7] += u.w >> 16;
    }
    uint4* dst = reinterpret_cast<uint4*>(counts + (size_t)b * R3 + k * 8);
    dst[0] = make_uint4(s[0], s[1], s[2], s[3]);
    dst[1] = make_uint4(s[4], s[5], s[6], s[7]);
}

// ---------------- Scatter: LDS packed-f16 atomic accumulation ----------------
// One block per (b, channel-pair). acc[R3] half2 = 128 KiB LDS.
// One ds_pk_add_f16 per point covers BOTH channels -> 33.6M DS lane-atomics total.
__global__ __launch_bounds__(1024, 1)
void scatter2_kernel(const float* __restrict__ features,
                     const int* __restrict__ idx,
                     const unsigned int* __restrict__ counts,
                     float* __restrict__ vox) {
    __shared__ unsigned int acc[R3];             // 32768 x (2 x f16) = 128 KiB
    const int bc2 = blockIdx.x;                  // b*32 + cpair
    const int b  = bc2 >> 5;
    const int c0 = (bc2 & 31) * 2;

    for (int v = threadIdx.x; v < R3 / 4; v += 1024)
        reinterpret_cast<uint4*>(acc)[v] = make_uint4(0u, 0u, 0u, 0u);
    __syncthreads();

    const unsigned int accbase = (unsigned int)(uintptr_t)acc;

    const float4* f0p = reinterpret_cast<const float4*>(
        features + ((size_t)b * CCH + c0) * NPTS);
    const float4* f1p = reinterpret_cast<const float4*>(
        features + ((size_t)b * CCH + c0 + 1) * NPTS);
    const int4* i4p = reinterpret_cast<const int4*>(idx + (size_t)b * NPTS);

    for (int g = threadIdx.x; g < NPTS4; g += 1024) {
        const float4 f0 = f0p[g];
        const float4 f1 = f1p[g];
        const int4 i = i4p[g];
        lds_pk_add_f16(accbase + 4u * (unsigned)i.x, pack_rtz(f0.x, f1.x));
        lds_pk_add_f16(accbase + 4u * (unsigned)i.y, pack_rtz(f0.y, f1.y));
        lds_pk_add_f16(accbase + 4u * (unsigned)i.z, pack_rtz(f0.z, f1.z));
        lds_pk_add_f16(accbase + 4u * (unsigned)i.w, pack_rtz(f0.w, f1.w));
    }
    __syncthreads();

    // writeout: fused divide, two coalesced float4 rows per iteration
    const uint4* c4 = reinterpret_cast<const uint4*>(counts + (size_t)b * R3);
    float* o0 = vox + ((size_t)b * CCH + c0) * R3;
    float* o1 = o0 + R3;
    for (int v = threadIdx.x; v < R3 / 4; v += 1024) {
        const uint4 u = reinterpret_cast<const uint4*>(acc)[v];   // 4 half2
        const uint4 c = c4[v];
        const float2 a0 = __half22float2(__builtin_bit_cast(__half2, u.x));
        const float2 a1 = __half22float2(__builtin_bit_cast(__half2, u.y));
        const float2 a2 = __half22float2(__builtin_bit_cast(__half2, u.z));
        const float2 a3 = __half22float2(__builtin_bit_cast(__half2, u.w));
        const float r0 = 1.f / fmaxf((float)c.x, 1.f);
        const float r1 = 1.f / fmaxf((float)c.y, 1.f);
        const float r2 = 1.f / fmaxf((float)c.z, 1.f);
        const float r3 = 1.f / fmaxf((float)c.w, 1.f);
        reinterpret_cast<float4*>(o0)[v] =
            make_float4(a0.x * r0, a1.x * r1, a2.x * r2, a3.x * r3);
        reinterpret_cast<float4*>(o1)[v] =
            make_float4(a0.y * r0, a1.y * r1, a2.y * r2, a3.y * r3);
    }
}

extern "C" void kernel_launch(void* const* d_in, const int* in_sizes, int n_in,
                              void* d_out, int out_size, void* d_ws, size_t ws_size,
                              hipStream_t stream) {
    const float* features = (const float*)d_in[0];   // [16,64,65536]
    const float* coords   = (const float*)d_in[1];   // [16,3,65536]

    float* vox      = (float*)d_out;                             // 33,554,432 f32
    float* out_norm = (float*)d_out + (size_t)BATCH * CCH * R3;  // 3,145,728 f32

    char* ws = (char*)d_ws;
    float*          sums     = (float*)ws;                    // 192 B
    unsigned int*   r2bits   = (unsigned int*)(ws + 192);     // 64 B
    size_t off = 256;
    int*            idx      = (int*)(ws + off);           off += (size_t)BATCH * NPTS * 4; // 4 MiB
    unsigned short* cnt_part = (unsigned short*)(ws + off); off += (size_t)128 * R3 * 2;    // 8 MiB
    unsigned int*   counts   = (unsigned int*)(ws + off);  off += (size_t)BATCH * R3 * 4;   // 2 MiB

    (void)hipMemsetAsync(ws, 0, 256, stream);

    statsA_kernel<<<256, 256, 0, stream>>>(coords, sums);
    statsB_kernel<<<256, 256, 0, stream>>>(coords, sums, r2bits);
    norm_cnt_kernel<<<128, 1024, 0, stream>>>(coords, sums, r2bits,
                                              out_norm, idx, cnt_part);
    reduce_counts_kernel<<<BATCH * (R3 / 8) / 256, 256, 0, stream>>>(cnt_part, counts);
    scatter2_kernel<<<BATCH * (CCH / 2), 1024, 0, stream>>>(features, idx, counts, vox);
}